// Round 5
// baseline (73.704 us; speedup 1.0000x reference)
//
#include <hip/hip_runtime.h>
#include <stdint.h>

// CRF log-likelihood, B=128, T=2048, K=96 on gfx950.
//
// Round 5: the chunked forward recurrence (verified rounds 3-4) was stalling
// ~3000 cyc/step on 16-line-divergent loads (batch-major layout) with only
// 2 waves/CU. New pipeline:
//   prep_trans: expT bf16 table (kills per-block exp(trans) startup)
//   prep:       stream fp32 input once -> exp -> bf16, regrouped
//               [g][t][bl][k'] so each wave's per-step 3KB is contiguous
//               (lane reads 3x dwordx4 from one dense slab); mask regrouped;
//               gold-path numerator fused here (rows are streaming through).
//   fwd:        128 chunks x 16 steps (+16 warm-up) = 1024 one-wave blocks
//               (4 waves/CU); renorm every 2nd step only (exponent range is
//               plenty); reads are L3-resident.
//   reduce:     final deterministic sum.
// Fallback to the verified round-4 kernels if ws_size is too small.

constexpr int K    = 96;
constexpr int B    = 128;
constexpr int G    = 8;     // batch groups of 16
constexpr int NBW  = 16;    // batches per wave
constexpr int WARM = 16;
constexpr int NCH  = 128;   // chunks (new path)
constexpr int TT   = 64;    // prepass t-tile

typedef __attribute__((ext_vector_type(8))) short bf16x8;
typedef __attribute__((ext_vector_type(4))) float f32x4;

__device__ __forceinline__ unsigned short f2bf(float f) {
  unsigned int b = __float_as_uint(f);
  return (unsigned short)((b + 0x7fff + ((b >> 16) & 1)) >> 16);  // RNE
}
__device__ __forceinline__ float bf2f(unsigned short h) {
  return __uint_as_float(((unsigned int)h) << 16);
}
__device__ __forceinline__ unsigned int cvt_pk_bf16(float lo, float hi) {
  unsigned int r;
  asm volatile("v_cvt_pk_bf16_f32 %0, %1, %2" : "=v"(r) : "v"(lo), "v"(hi));
  return r;
}
__device__ __forceinline__ float lane_bcast(int addr4, float v) {
  return __int_as_float(__builtin_amdgcn_ds_bpermute(addr4, __float_as_int(v)));
}

// ---------------- expT table ----------------
__global__ __launch_bounds__(256) void prep_trans(
    const float* __restrict__ trans, unsigned short* __restrict__ ebT)
{
  const int i = blockIdx.x * 256 + threadIdx.x;
  if (i < K * K) ebT[i] = f2bf(__expf(trans[i]));
}

// ---------------- emissions prepass + fused numerator ----------------
__global__ __launch_bounds__(256) void prep(
    const float* __restrict__ inp, const int* __restrict__ tags,
    const int* __restrict__ mask, const float* __restrict__ trans,
    unsigned short* __restrict__ eb, float* __restrict__ mf,
    float* __restrict__ pnum, float* __restrict__ pcnt, int T, int ntiles)
{
  const int b = blockIdx.x, tile = blockIdx.y, tid = threadIdx.x;
  const int t0 = tile * TT;
  const int g = b >> 4, bl = b & 15;

  __shared__ int   tgs[TT + 1];
  __shared__ float mks[TT + 1];
  if (tid <= TT) {
    const int t = t0 + tid;
    tgs[tid] = (t < T) ? tags[(size_t)b * T + t] : 0;
    mks[tid] = (t < T) ? (float)mask[(size_t)b * T + t] : 0.f;
  }
  __syncthreads();

  const float4* src = (const float4*)(inp + ((size_t)b * T + t0) * K);
  unsigned short* dst = eb + ((size_t)(g * T + t0) * NBW + bl) * K;
  float nacc = 0.f, mcnt = 0.f;
  #pragma unroll
  for (int i = 0; i < (TT * K / 4) / 256; ++i) {   // 6
    const int idx = tid + i * 256;
    const int f = idx * 4;
    const int q = (f * 683) >> 16;   // f / 96  (f < 6144)
    const int k = f - 96 * q;
    float4 v = src[idx];
    const int tg = tgs[q];
    if (t0 + q < T - 1 && (unsigned)(tg - k) < 4u) {
      const float pick = (tg == k) ? v.x : (tg == k + 1) ? v.y
                        : (tg == k + 2) ? v.z : v.w;
      nacc += pick * mks[q];
    }
    // k-permutation: k' = ((k%16)/4)*24 + (k/16)*4 + (k%4); float4 is 4-aligned
    const int kp = ((k & 15) >> 2) * 24 + (k >> 4) * 4;
    uint2 pk;
    pk.x = cvt_pk_bf16(__expf(v.x), __expf(v.y));
    pk.y = cvt_pk_bf16(__expf(v.z), __expf(v.w));
    *(uint2*)(dst + (size_t)q * (NBW * K) + kp) = pk;
  }
  if (tid < TT) {
    const int t = t0 + tid;
    mcnt = mks[tid];
    if (t < T - 1) nacc += trans[tgs[tid] * K + tgs[tid + 1]] * mks[tid + 1];
    mf[((size_t)(g * T) + t) * NBW + bl] = mks[tid];
  }
  __shared__ float r1[256], r2[256];
  r1[tid] = nacc; r2[tid] = mcnt;
  __syncthreads();
  #pragma unroll
  for (int st = 128; st > 0; st >>= 1) {
    if (tid < st) { r1[tid] += r1[tid + st]; r2[tid] += r2[tid + st]; }
    __syncthreads();
  }
  if (tid == 0) { pnum[b * ntiles + tile] = r1[0]; pcnt[b * ntiles + tile] = r2[0]; }
}

// ---------------- chunked forward ----------------
__global__ __launch_bounds__(64, 1) void fwd(
    const unsigned short* __restrict__ eb,   // [G][T][16][96'] bf16 exp(emit)
    const unsigned short* __restrict__ ebT,  // [96][96] bf16 exp(trans)
    const float* __restrict__ mf,            // [G][T][16]
    float* __restrict__ pden,                // [NCH][B]
    int T, int clen)
{
  const int l  = threadIdx.x;
  const int bl = l & 15;
  const int hi = l >> 4;
  const int g  = blockIdx.x;
  const int c  = blockIdx.y;
  const int bcast = bl * 4;

  const int s_init = (c == 0) ? 0 : (c * clen - WARM);
  const int s_A    = c * clen;
  const int s_end  = min(c * clen + clen, T - 1);

  __shared__ unsigned short Xs[NBW][104];

  // A fragments from expT table: A[row=j][k=i] = expT[i][j]
  bf16x8 A[6][3];
  #pragma unroll
  for (int jt = 0; jt < 6; ++jt) {
    #pragma unroll
    for (int kf = 0; kf < 3; ++kf) {
      #pragma unroll
      for (int e = 0; e < 8; ++e)
        A[jt][kf][e] = (short)ebT[(kf * 32 + hi * 8 + e) * K + jt * 16 + bl];
    }
  }

  const unsigned short* ebg = eb + (size_t)g * T * (NBW * K);
  const float* mfg = mf + (size_t)g * T * NBW;

  auto eaddr = [&](int s) {
    return (const uint4*)(ebg + (size_t)s * (NBW * K) + bl * K + hi * 24);
  };

  // ---- init at s_init: x = e0 / e0[k=0]; Mref = log(e0[k=0]) ----
  double Mref;
  {
    const uint4* p = eaddr(s_init);
    const uint4 Ea = p[0], Eb2 = p[1], Ec = p[2];
    const uint32_t uw[12] = {Ea.x, Ea.y, Ea.z, Ea.w, Eb2.x, Eb2.y, Eb2.z, Eb2.w,
                             Ec.x, Ec.y, Ec.z, Ec.w};
    float e[24];
    #pragma unroll
    for (int w = 0; w < 12; ++w) {
      e[2 * w]     = __uint_as_float(uw[w] << 16);
      e[2 * w + 1] = __uint_as_float(uw[w] & 0xffff0000u);
    }
    const float r0  = lane_bcast(bcast, e[0]);
    const float inv = 1.0f / r0;
    Mref = (double)__logf(r0);
    #pragma unroll
    for (int jt = 0; jt < 6; ++jt) {
      uint2 pk;
      pk.x = cvt_pk_bf16(e[jt * 4 + 0] * inv, e[jt * 4 + 1] * inv);
      pk.y = cvt_pk_bf16(e[jt * 4 + 2] * inv, e[jt * 4 + 3] * inv);
      *(uint2*)&Xs[bl][jt * 16 + hi * 4] = pk;
    }
  }

  bf16x8 Bf[3];
  #pragma unroll
  for (int kf = 0; kf < 3; ++kf)
    Bf[kf] = *(const bf16x8*)&Xs[bl][kf * 32 + hi * 8];

  uint4 A0[3], A1[3], B0[3], B1[3];
  float mA0 = 0, mA1 = 0, mB0 = 0, mB1 = 0;

  auto loadE = [&](int s, uint4 (&E)[3], float& m) {
    if (s <= s_end) {
      const uint4* p = eaddr(s);
      E[0] = p[0]; E[1] = p[1]; E[2] = p[2];
      m = mfg[(size_t)s * NBW + bl];
    }
  };

  auto dostep = [&](const uint4 (&E)[3], float m, bool renorm) {
    f32x4 acc[6];
    #pragma unroll
    for (int jt = 0; jt < 6; ++jt) {
      f32x4 a = {0.f, 0.f, 0.f, 0.f};
      a = __builtin_amdgcn_mfma_f32_16x16x32_bf16(A[jt][0], Bf[0], a, 0, 0, 0);
      a = __builtin_amdgcn_mfma_f32_16x16x32_bf16(A[jt][1], Bf[1], a, 0, 0, 0);
      a = __builtin_amdgcn_mfma_f32_16x16x32_bf16(A[jt][2], Bf[2], a, 0, 0, 0);
      acc[jt] = a;
    }
    const bool mm = (m != 0.f);
    float inv = 1.0f;
    if (renorm) {
      const float r = lane_bcast(bcast, acc[0][0]);   // C[0][b]
      inv = 1.0f / r;
      if (mm) Mref += (double)__logf(r);
    }
    if (mm) {
      const uint32_t uw[12] = {E[0].x, E[0].y, E[0].z, E[0].w,
                               E[1].x, E[1].y, E[1].z, E[1].w,
                               E[2].x, E[2].y, E[2].z, E[2].w};
      #pragma unroll
      for (int jt = 0; jt < 6; ++jt) {
        const uint32_t u0 = uw[jt * 2], u1 = uw[jt * 2 + 1];
        const float e0 = __uint_as_float(u0 << 16);
        const float e1 = __uint_as_float(u0 & 0xffff0000u);
        const float e2 = __uint_as_float(u1 << 16);
        const float e3 = __uint_as_float(u1 & 0xffff0000u);
        const f32x4 a = acc[jt];
        uint2 pk;
        pk.x = cvt_pk_bf16(a[0] * inv * e0, a[1] * inv * e1);
        pk.y = cvt_pk_bf16(a[2] * inv * e2, a[3] * inv * e3);
        *(uint2*)&Xs[bl][jt * 16 + hi * 4] = pk;
      }
    }
    #pragma unroll
    for (int kf = 0; kf < 3; ++kf)
      Bf[kf] = *(const bf16x8*)&Xs[bl][kf * 32 + hi * 8];
  };

  auto phi = [&]() -> double {
    float sum = 0.f;
    #pragma unroll
    for (int u = 0; u < 24; ++u) sum += bf2f(Xs[bl][hi * 24 + u]);
    sum += __shfl_xor(sum, 16);
    sum += __shfl_xor(sum, 32);
    return Mref + (double)__logf(sum);
  };

  double phiA = 0.0;   // c==0: Phi before chunk is 0 by construction
  loadE(s_init + 1, A0, mA0); loadE(s_init + 2, A1, mA1);
  loadE(s_init + 3, B0, mB0); loadE(s_init + 4, B1, mB1);

  int s = s_init + 1;
  while (s + 3 <= s_end) {
    dostep(A0, mA0, false); dostep(A1, mA1, true);
    if (s + 1 == s_A) phiA = phi();
    loadE(s + 4, A0, mA0); loadE(s + 5, A1, mA1);
    s += 2;
    dostep(B0, mB0, false); dostep(B1, mB1, true);
    if (s + 1 == s_A) phiA = phi();
    loadE(s + 4, B0, mB0); loadE(s + 5, B1, mB1);
    s += 2;
  }
  bool usedA = false;
  if (s + 1 <= s_end) {
    dostep(A0, mA0, false); dostep(A1, mA1, true);
    if (s + 1 == s_A) phiA = phi();
    s += 2; usedA = true;
  }
  if (s <= s_end) {
    if (usedA) dostep(B0, mB0, true);
    else       dostep(A0, mA0, true);
  }
  const double phiB = phi();

  if (hi == 0) pden[c * B + g * NBW + bl] = (float)(phiB - phiA);
}

// ---------------- final reduce ----------------
__global__ __launch_bounds__(128) void reduce_new(
    const float* __restrict__ inp, const int* __restrict__ tags,
    const int* __restrict__ mask,
    const float* __restrict__ pden, const float* __restrict__ pnum,
    const float* __restrict__ pcnt, float* __restrict__ out, int T, int ntiles)
{
  const int b = threadIdx.x;
  float den = 0.f;
  for (int c = 0; c < NCH; ++c) den += pden[c * B + b];
  float num = 0.f, cnt = 0.f;
  for (int i = 0; i < ntiles; ++i) {
    num += pnum[b * ntiles + i];
    cnt += pcnt[b * ntiles + i];
  }
  const int last = (int)cnt - 1;
  float last_sc = 0.f;
  if (last >= 0) {
    const int lt = tags[(size_t)b * T + last];
    last_sc = inp[((size_t)b * T + (T - 1)) * K + lt]
            * (float)mask[(size_t)b * T + T - 1];
  }
  __shared__ float red[128];
  red[b] = num + last_sc - den;
  __syncthreads();
  #pragma unroll
  for (int st = 64; st > 0; st >>= 1) {
    if (b < st) red[b] += red[b + st];
    __syncthreads();
  }
  if (b == 0) out[0] = red[0];
}

// ================= fallback: verified round-4 path =================
constexpr int FCH = 64;
constexpr int FCL = 32;

__global__ __launch_bounds__(64, 1) void fb_fwd_chunk(
    const float* __restrict__ inp, const int* __restrict__ tags,
    const int* __restrict__ mask, const float* __restrict__ trans,
    float* __restrict__ pden, float* __restrict__ pnum,
    float* __restrict__ pcnt, int T)
{
  const int l  = threadIdx.x;
  const int bl = l & 15;
  const int hi = l >> 4;
  const int g  = blockIdx.x;
  const int c  = blockIdx.y;
  const int b  = g * NBW + bl;
  const int bcast = bl * 4;

  const int s_init = (c == 0) ? 0 : (c * FCL - WARM);
  const int s_A    = c * FCL;
  const int s_end  = min(c * FCL + FCL, T - 1);

  __shared__ unsigned short Xs[NBW][104];

  bf16x8 A[6][3];
  #pragma unroll
  for (int jt = 0; jt < 6; ++jt) {
    #pragma unroll
    for (int kf = 0; kf < 3; ++kf) {
      const int j = jt * 16 + bl;
      #pragma unroll
      for (int e = 0; e < 8; ++e) {
        const int i = kf * 32 + hi * 8 + e;
        A[jt][kf][e] = (short)f2bf(__expf(trans[i * K + j]));
      }
    }
  }

  const float* ib  = inp  + (size_t)b * T * K;
  const int*   mb  = mask + (size_t)b * T;
  const int*   tgb = tags + (size_t)b * T;

  {
    const float* i0 = ib + (size_t)s_init * K;
    float4 e0[6];
    #pragma unroll
    for (int jt = 0; jt < 6; ++jt) {
      float4 v = *(const float4*)(i0 + jt * 16 + hi * 4);
      v.x = __expf(v.x); v.y = __expf(v.y); v.z = __expf(v.z); v.w = __expf(v.w);
      e0[jt] = v;
    }
    const float r0  = lane_bcast(bcast, e0[0].x);
    const float inv = 1.0f / r0;
    #pragma unroll
    for (int jt = 0; jt < 6; ++jt) {
      uint2 p;
      p.x = cvt_pk_bf16(e0[jt].x * inv, e0[jt].y * inv);
      p.y = cvt_pk_bf16(e0[jt].z * inv, e0[jt].w * inv);
      *(uint2*)&Xs[bl][jt * 16 + hi * 4] = p;
    }
  }
  double Mref = (double)ib[(size_t)s_init * K];

  bf16x8 Bf[3];
  #pragma unroll
  for (int kf = 0; kf < 3; ++kf)
    Bf[kf] = *(const bf16x8*)&Xs[bl][kf * 32 + hi * 8];

  float4 e0b[6], e1b[6], e2b[6];
  int    m0 = 0, m1 = 0, m2 = 0;

  auto load = [&](int s, float4 (&e)[6], int& m) {
    #pragma unroll
    for (int jt = 0; jt < 6; ++jt)
      e[jt] = *(const float4*)(ib + (size_t)s * K + jt * 16 + hi * 4);
    m = mb[s];
  };

  auto step = [&](int s, float4 (&ebuf)[6], int& msl) {
    f32x4 acc[6];
    #pragma unroll
    for (int jt = 0; jt < 6; ++jt) {
      f32x4 a = {0.f, 0.f, 0.f, 0.f};
      a = __builtin_amdgcn_mfma_f32_16x16x32_bf16(A[jt][0], Bf[0], a, 0, 0, 0);
      a = __builtin_amdgcn_mfma_f32_16x16x32_bf16(A[jt][1], Bf[1], a, 0, 0, 0);
      a = __builtin_amdgcn_mfma_f32_16x16x32_bf16(A[jt][2], Bf[2], a, 0, 0, 0);
      acc[jt] = a;
    }
    const float r   = lane_bcast(bcast, acc[0][0]);
    const float inv = 1.0f / r;
    const bool  mm  = msl != 0;
    if (mm) Mref += (double)__logf(r);

    float xv[6][4];
    #pragma unroll
    for (int jt = 0; jt < 6; ++jt) {
      float4 e4 = ebuf[jt];
      e4.x = __expf(e4.x); e4.y = __expf(e4.y);
      e4.z = __expf(e4.z); e4.w = __expf(e4.w);
      xv[jt][0] = acc[jt][0] * (e4.x * inv);
      xv[jt][1] = acc[jt][1] * (e4.y * inv);
      xv[jt][2] = acc[jt][2] * (e4.z * inv);
      xv[jt][3] = acc[jt][3] * (e4.w * inv);
    }
    if (s + 3 <= s_end) load(s + 3, ebuf, msl);
    if (mm) {
      #pragma unroll
      for (int jt = 0; jt < 6; ++jt) {
        uint2 p;
        p.x = cvt_pk_bf16(xv[jt][0], xv[jt][1]);
        p.y = cvt_pk_bf16(xv[jt][2], xv[jt][3]);
        *(uint2*)&Xs[bl][jt * 16 + hi * 4] = p;
      }
    }
    #pragma unroll
    for (int kf = 0; kf < 3; ++kf)
      Bf[kf] = *(const bf16x8*)&Xs[bl][kf * 32 + hi * 8];
  };

  auto phi = [&]() -> double {
    float sum = 0.f;
    #pragma unroll
    for (int u = 0; u < 24; ++u) sum += bf2f(Xs[bl][hi * 24 + u]);
    sum += __shfl_xor(sum, 16);
    sum += __shfl_xor(sum, 32);
    return Mref + (double)__logf(sum);
  };

  load(s_init + 1, e0b, m0);
  load(s_init + 2, e1b, m1);
  load(s_init + 3, e2b, m2);

  double phiA = 0.0;
  int s = s_init + 1;
  for (; s + 2 <= s_end; s += 3) {
    step(s,     e0b, m0); if (s     == s_A) phiA = phi();
    step(s + 1, e1b, m1); if (s + 1 == s_A) phiA = phi();
    step(s + 2, e2b, m2); if (s + 2 == s_A) phiA = phi();
  }
  if (s <= s_end) { step(s, e0b, m0); ++s; }
  if (s <= s_end) { step(s, e1b, m1); ++s; }
  const double phiB = phi();

  if (hi == 0) pden[c * B + b] = (float)(phiB - phiA);

  const int t0 = c * FCL;
  float nacc = 0.f, mcnt = 0.f;
  #pragma unroll
  for (int k = 0; k < FCL / 4; ++k) {
    const int t  = t0 + 4 * k + hi;
    const int mt = mb[t];
    mcnt += (float)mt;
    if (t < T - 1) {
      const int tg  = tgb[t];
      const int tg1 = tgb[t + 1];
      nacc = fmaf(trans[tg * K + tg1], (float)mb[t + 1], nacc);
      nacc = fmaf(ib[(size_t)t * K + tg], (float)mt, nacc);
    }
  }
  nacc += __shfl_xor(nacc, 16); nacc += __shfl_xor(nacc, 32);
  mcnt += __shfl_xor(mcnt, 16); mcnt += __shfl_xor(mcnt, 32);
  if (hi == 0) {
    pnum[c * B + b] = nacc;
    pcnt[c * B + b] = mcnt;
  }
}

__global__ __launch_bounds__(128) void fb_reduce(
    const float* __restrict__ inp, const int* __restrict__ tags,
    const int* __restrict__ mask,
    const float* __restrict__ pden, const float* __restrict__ pnum,
    const float* __restrict__ pcnt, float* __restrict__ out, int T)
{
  const int b = threadIdx.x;
  float den = 0.f, num = 0.f, cnt = 0.f;
  for (int c = 0; c < FCH; ++c) {
    den += pden[c * B + b];
    num += pnum[c * B + b];
    cnt += pcnt[c * B + b];
  }
  const int last_idx = (int)cnt - 1;
  float last_sc = 0.f;
  if (last_idx >= 0) {
    const int lt = tags[(size_t)b * T + last_idx];
    last_sc = inp[((size_t)b * T + (T - 1)) * K + lt]
            * (float)mask[(size_t)b * T + T - 1];
  }
  __shared__ float red[128];
  red[b] = num + last_sc - den;
  __syncthreads();
  #pragma unroll
  for (int s = 64; s > 0; s >>= 1) {
    if (b < s) red[b] += red[b + s];
    __syncthreads();
  }
  if (b == 0) out[0] = red[0];
}

extern "C" void kernel_launch(void* const* d_in, const int* in_sizes, int n_in,
                              void* d_out, int out_size, void* d_ws, size_t ws_size,
                              hipStream_t stream)
{
  const float* inp   = (const float*)d_in[0];
  const int*   tags  = (const int*)  d_in[1];
  const int*   mask  = (const int*)  d_in[2];
  const float* trans = (const float*)d_in[3];
  float*       out   = (float*)d_out;

  const int BT = in_sizes[1];
  const int T  = BT / B;        // 2048
  const int ntiles = T / TT;    // 32

  auto align256 = [](size_t x) { return (x + 255) & ~(size_t)255; };
  size_t off = 0;
  float* pden = (float*)((char*)d_ws + off); off = align256(off + (size_t)NCH * B * 4);
  float* pnum = (float*)((char*)d_ws + off); off = align256(off + (size_t)B * ntiles * 4);
  float* pcnt = (float*)((char*)d_ws + off); off = align256(off + (size_t)B * ntiles * 4);
  unsigned short* ebT = (unsigned short*)((char*)d_ws + off); off = align256(off + (size_t)K * K * 2);
  float* mf = (float*)((char*)d_ws + off); off = align256(off + (size_t)G * T * NBW * 4);
  unsigned short* eb = (unsigned short*)((char*)d_ws + off); off = align256(off + (size_t)G * T * NBW * K * 2);
  const size_t need = off;

  const bool ok = (ws_size >= need) && (T % NCH == 0) && (T % TT == 0) && (T / NCH >= 4);

  if (ok) {
    const int clen = T / NCH;   // 16
    prep_trans<<<(K * K + 255) / 256, 256, 0, stream>>>(trans, ebT);
    dim3 pgrid(B, ntiles);
    prep<<<pgrid, 256, 0, stream>>>(inp, tags, mask, trans, eb, mf,
                                    pnum, pcnt, T, ntiles);
    dim3 fgrid(G, NCH);
    fwd<<<fgrid, 64, 0, stream>>>(eb, ebT, mf, pden, T, clen);
    reduce_new<<<1, 128, 0, stream>>>(inp, tags, mask, pden, pnum, pcnt,
                                      out, T, ntiles);
  } else {
    float* fpden = (float*)d_ws;
    float* fpnum = fpden + FCH * B;
    float* fpcnt = fpnum + FCH * B;
    dim3 grid(B / NBW, FCH);
    fb_fwd_chunk<<<grid, 64, 0, stream>>>(inp, tags, mask, trans,
                                          fpden, fpnum, fpcnt, T);
    fb_reduce<<<1, 128, 0, stream>>>(inp, tags, mask, fpden, fpnum, fpcnt,
                                     out, T);
  }

  (void)n_in; (void)out_size;
}